// Round 8
// baseline (410.650 us; speedup 1.0000x reference)
//
#include <hip/hip_runtime.h>

#define NUM_CLASSES 21
#define HW (512 * 512)            // 2^18 px per image
#define NBATCH 8
#define TOTAL_PIX (NBATCH * HW)   // 2^21
#define SMOOTH 1e-6f
#define THREADS 512
#define PXPT 4                    // px per thread (float4)
#define PXPB (THREADS * PXPT)     // 2048 px per block
#define NBLK (TOTAL_PIX / PXPB)   // 1024 blocks; 128 per image exactly
#define REPS 8                    // measurement probe: redo the work 8x, counts become 8x (exact)

// d_ws layout (u32): part[3][NUM_CLASSES][NBLK]  (row 0=pred,1=tgt,2=inter), values are REPS x true counts.
// No zero-init needed: every slot read is unconditionally written first.

__global__ __launch_bounds__(THREADS) void iou_hist_probe(const float* __restrict__ pred,
                                                          const int* __restrict__ target,
                                                          unsigned int* __restrict__ part) {
    __shared__ unsigned int s_pi[NUM_CLASSES];   // lo16 = pred cnt, hi16 = inter; max 8*2048=16384 < 2^16
    __shared__ unsigned int s_tgt[NUM_CLASSES];

    const int tid = threadIdx.x;
    if (tid < NUM_CLASSES) { s_pi[tid] = 0u; s_tgt[tid] = 0u; }
    __syncthreads();

    const int blk = blockIdx.x;
    const int b = blk >> 7;                     // image index (block-uniform)
    const int ib = (blk & 127) * PXPB;          // base pixel in image (block-uniform)
    const float* base = pred + (((size_t)b * NUM_CLASSES) << 18) + ib;
    const int off = tid * PXPT;

    const int4 t = *reinterpret_cast<const int4*>(target + ((size_t)b << 18) + ib + off);

#pragma unroll 1
    for (int r = 0; r < REPS; ++r) {
        // Compiler memory barrier: forces all 21 loads to be RE-ISSUED each rep
        // (otherwise reps 2..8 would CSE against rep 1's values and measure nothing).
        asm volatile("" ::: "memory");

        float4 w[NUM_CLASSES];
#pragma unroll
        for (int c = 0; c < NUM_CLASSES; ++c)
            w[c] = *reinterpret_cast<const float4*>(base + ((size_t)c << 18) + off);

        float bv0 = w[0].x, bv1 = w[0].y, bv2 = w[0].z, bv3 = w[0].w;
        int bi0 = 0, bi1 = 0, bi2 = 0, bi3 = 0;
#pragma unroll
        for (int c = 1; c < NUM_CLASSES; ++c) {
            if (w[c].x > bv0) { bv0 = w[c].x; bi0 = c; }   // strict > == first-max (jnp.argmax)
            if (w[c].y > bv1) { bv1 = w[c].y; bi1 = c; }
            if (w[c].z > bv2) { bv2 = w[c].z; bi2 = c; }
            if (w[c].w > bv3) { bv3 = w[c].w; bi3 = c; }
        }

        atomicAdd(&s_pi[bi0], 1u + (bi0 == t.x ? 0x10000u : 0u));
        atomicAdd(&s_pi[bi1], 1u + (bi1 == t.y ? 0x10000u : 0u));
        atomicAdd(&s_pi[bi2], 1u + (bi2 == t.z ? 0x10000u : 0u));
        atomicAdd(&s_pi[bi3], 1u + (bi3 == t.w ? 0x10000u : 0u));
        atomicAdd(&s_tgt[t.x], 1u);
        atomicAdd(&s_tgt[t.y], 1u);
        atomicAdd(&s_tgt[t.z], 1u);
        atomicAdd(&s_tgt[t.w], 1u);
    }

    __syncthreads();
    if (tid < NUM_CLASSES) {
        unsigned int pi = s_pi[tid];
        part[(0 * NUM_CLASSES + tid) * NBLK + blk] = pi & 0xFFFFu;   // 8x counts
        part[(1 * NUM_CLASSES + tid) * NBLK + blk] = s_tgt[tid];
        part[(2 * NUM_CLASSES + tid) * NBLK + blk] = pi >> 16;
    }
}

// Fused reduce: one block sums all 21 classes, divides by REPS (exact integer >>3),
// computes per-class IoU and the mean. Replaces the old reduce1+reduce2 pair.
__global__ __launch_bounds__(256) void iou_reduce(const unsigned int* __restrict__ part,
                                                  float* __restrict__ out) {
    __shared__ unsigned int ls[3][4];
    const int tid = threadIdx.x;
    const int w = tid >> 6, lane = tid & 63;
    float acc = 0.0f;                          // live only on thread 0

    for (int c = 0; c < NUM_CLASSES; ++c) {
        // each row is NBLK=1024 u32 = 256 uint4: one uint4 per thread
        uint4 a = reinterpret_cast<const uint4*>(part + (0 * NUM_CLASSES + c) * NBLK)[tid];
        uint4 bb = reinterpret_cast<const uint4*>(part + (1 * NUM_CLASSES + c) * NBLK)[tid];
        uint4 d = reinterpret_cast<const uint4*>(part + (2 * NUM_CLASSES + c) * NBLK)[tid];
        unsigned int s0 = a.x + a.y + a.z + a.w;
        unsigned int s1 = bb.x + bb.y + bb.z + bb.w;
        unsigned int s2 = d.x + d.y + d.z + d.w;
#pragma unroll
        for (int o = 32; o > 0; o >>= 1) {
            s0 += __shfl_down(s0, o);
            s1 += __shfl_down(s1, o);
            s2 += __shfl_down(s2, o);
        }
        if (lane == 0) { ls[0][w] = s0; ls[1][w] = s1; ls[2][w] = s2; }
        __syncthreads();
        if (tid == 0) {
            unsigned int t0 = (ls[0][0] + ls[0][1] + ls[0][2] + ls[0][3]) >> 3;  // /REPS, exact
            unsigned int t1 = (ls[1][0] + ls[1][1] + ls[1][2] + ls[1][3]) >> 3;
            unsigned int t2 = (ls[2][0] + ls[2][1] + ls[2][2] + ls[2][3]) >> 3;
            float inter = (float)t2;
            float uni = (float)t0 + (float)t1 - inter;
            acc += (inter + SMOOTH) / (uni + SMOOTH);
        }
        __syncthreads();                       // protect ls before next class overwrites
    }
    if (tid == 0) out[0] = acc * (1.0f / NUM_CLASSES);
}

extern "C" void kernel_launch(void* const* d_in, const int* in_sizes, int n_in,
                              void* d_out, int out_size, void* d_ws, size_t ws_size,
                              hipStream_t stream) {
    const float* pred = (const float*)d_in[0];
    const int* target = (const int*)d_in[1];
    float* out = (float*)d_out;
    unsigned int* part = (unsigned int*)d_ws;

    iou_hist_probe<<<NBLK, THREADS, 0, stream>>>(pred, target, part);
    iou_reduce<<<1, 256, 0, stream>>>(part, out);
}

// Round 9
// 247.025 us; speedup vs baseline: 1.6624x; 1.6624x over previous
//
#include <hip/hip_runtime.h>

#define NUM_CLASSES 21
#define HW (512 * 512)            // 2^18 px per image
#define NBATCH 8
#define TOTAL_PIX (NBATCH * HW)   // 2^21
#define SMOOTH 1e-6f
#define THREADS 512
#define PXPT 4                    // px per thread (float4)
#define PXPB (THREADS * PXPT)     // 2048 px per block
#define NBLK (TOTAL_PIX / PXPB)   // 1024 blocks; 128 per image exactly

// d_ws layout (u32): part[3][NUM_CLASSES][NBLK]  (row 0=pred,1=tgt,2=inter)
// No zero-init needed: every slot read is unconditionally written first.
//
// R8 probe evidence: hist consumes 184 MB at ~6.45 TB/s (8x-rep probe: 228 us,
// 28.5 us/rep, VALUBusy 11%, bank conflicts negligible) -> single-shot hist is
// at the memory roofline (~29-32 us). Remaining end-to-end time is harness
// ws-poison (102 us measured) + input restore (~58 us) + dispatch gaps.

__global__ __launch_bounds__(THREADS) void iou_hist(const float* __restrict__ pred,
                                                    const int* __restrict__ target,
                                                    unsigned int* __restrict__ part) {
    __shared__ unsigned int s_pi[NUM_CLASSES];   // lo16 = pred cnt, hi16 = inter (block max 2048 < 2^16)
    __shared__ unsigned int s_tgt[NUM_CLASSES];

    const int tid = threadIdx.x;
    if (tid < NUM_CLASSES) { s_pi[tid] = 0u; s_tgt[tid] = 0u; }
    __syncthreads();

    const int blk = blockIdx.x;
    const int b = blk >> 7;                     // image index (block-uniform)
    const int ib = (blk & 127) * PXPB;          // base pixel in image (block-uniform)
    const float* base = pred + (((size_t)b * NUM_CLASSES) << 18) + ib;
    const int off = tid * PXPT;                 // per-lane 16 B granularity

    float4 w[NUM_CLASSES];
#pragma unroll
    for (int c = 0; c < NUM_CLASSES; ++c)
        w[c] = *reinterpret_cast<const float4*>(base + ((size_t)c << 18) + off);

    float bv0 = w[0].x, bv1 = w[0].y, bv2 = w[0].z, bv3 = w[0].w;
    int bi0 = 0, bi1 = 0, bi2 = 0, bi3 = 0;
#pragma unroll
    for (int c = 1; c < NUM_CLASSES; ++c) {
        if (w[c].x > bv0) { bv0 = w[c].x; bi0 = c; }   // strict > == first-max (jnp.argmax)
        if (w[c].y > bv1) { bv1 = w[c].y; bi1 = c; }
        if (w[c].z > bv2) { bv2 = w[c].z; bi2 = c; }
        if (w[c].w > bv3) { bv3 = w[c].w; bi3 = c; }
    }

    const int4 t = *reinterpret_cast<const int4*>(target + ((size_t)b << 18) + ib + off);

    atomicAdd(&s_pi[bi0], 1u + (bi0 == t.x ? 0x10000u : 0u));
    atomicAdd(&s_pi[bi1], 1u + (bi1 == t.y ? 0x10000u : 0u));
    atomicAdd(&s_pi[bi2], 1u + (bi2 == t.z ? 0x10000u : 0u));
    atomicAdd(&s_pi[bi3], 1u + (bi3 == t.w ? 0x10000u : 0u));
    atomicAdd(&s_tgt[t.x], 1u);
    atomicAdd(&s_tgt[t.y], 1u);
    atomicAdd(&s_tgt[t.z], 1u);
    atomicAdd(&s_tgt[t.w], 1u);

    __syncthreads();
    if (tid < NUM_CLASSES) {
        unsigned int pi = s_pi[tid];
        // plain stores, class-major so reduce reads are contiguous — no global atomics
        part[(0 * NUM_CLASSES + tid) * NBLK + blk] = pi & 0xFFFFu;
        part[(1 * NUM_CLASSES + tid) * NBLK + blk] = s_tgt[tid];
        part[(2 * NUM_CLASSES + tid) * NBLK + blk] = pi >> 16;
    }
}

// Fused final reduce: one block, 16 waves; wave w owns classes c = w, w+16.
// Each wave sums the 3 rows (1024 u32 each) for its class, computes IoU into LDS;
// wave 0 then means the 21 IoUs. Only 1 barrier.
__global__ __launch_bounds__(1024) void iou_reduce(const unsigned int* __restrict__ part,
                                                   float* __restrict__ out) {
    __shared__ float s_iou[NUM_CLASSES];
    const int tid = threadIdx.x;
    const int wv = tid >> 6;            // 0..15
    const int lane = tid & 63;

    for (int c = wv; c < NUM_CLASSES; c += 16) {
        const uint4* p0 = reinterpret_cast<const uint4*>(part + (0 * NUM_CLASSES + c) * NBLK);
        const uint4* p1 = reinterpret_cast<const uint4*>(part + (1 * NUM_CLASSES + c) * NBLK);
        const uint4* p2 = reinterpret_cast<const uint4*>(part + (2 * NUM_CLASSES + c) * NBLK);
        unsigned int s0 = 0, s1 = 0, s2 = 0;
#pragma unroll
        for (int k = lane; k < NBLK / 4; k += 64) {    // 256 uint4 per row, 4 per lane
            uint4 a = p0[k]; s0 += a.x + a.y + a.z + a.w;
            uint4 bb = p1[k]; s1 += bb.x + bb.y + bb.z + bb.w;
            uint4 d = p2[k]; s2 += d.x + d.y + d.z + d.w;
        }
#pragma unroll
        for (int o = 32; o > 0; o >>= 1) {
            s0 += __shfl_down(s0, o);
            s1 += __shfl_down(s1, o);
            s2 += __shfl_down(s2, o);
        }
        if (lane == 0) {
            float inter = (float)s2;
            float uni = (float)s0 + (float)s1 - inter;
            s_iou[c] = (inter + SMOOTH) / (uni + SMOOTH);
        }
    }
    __syncthreads();
    if (tid < 64) {
        float v = tid < NUM_CLASSES ? s_iou[tid] : 0.0f;
#pragma unroll
        for (int o = 32; o > 0; o >>= 1) v += __shfl_down(v, o);
        if (tid == 0) out[0] = v * (1.0f / NUM_CLASSES);
    }
}

extern "C" void kernel_launch(void* const* d_in, const int* in_sizes, int n_in,
                              void* d_out, int out_size, void* d_ws, size_t ws_size,
                              hipStream_t stream) {
    const float* pred = (const float*)d_in[0];
    const int* target = (const int*)d_in[1];
    float* out = (float*)d_out;
    unsigned int* part = (unsigned int*)d_ws;

    iou_hist<<<NBLK, THREADS, 0, stream>>>(pred, target, part);
    iou_reduce<<<1, 1024, 0, stream>>>(part, out);
}